// Round 2
// baseline (227.102 us; speedup 1.0000x reference)
//
#include <hip/hip_runtime.h>
#include <math.h>

#define BN_EPS 1e-5f
#define NEG_SLOPE 0.2f

__device__ __forceinline__ float relu_f(float x) { return x > 0.f ? x : 0.f; }
__device__ __forceinline__ float leaky_f(float z) { return z > 0.f ? z : NEG_SLOPE * z; }

// ---------------- conv1 (3->64, 3x3 SAME) fused bias+BN+ReLU+2x2maxpool ----------------
// grid 512 = b(8) x cog(16) x q(4); 256 threads = one pooled position, 4 co
__global__ void conv1_pool(const float* __restrict__ img, const float* __restrict__ w,
                           const float* __restrict__ cb, const float* __restrict__ g,
                           const float* __restrict__ bb, const float* __restrict__ m,
                           const float* __restrict__ vv, float* __restrict__ out)
{
    int blk = blockIdx.x;
    int q = blk & 3, cog = (blk >> 2) & 15, b = blk >> 6;
    int t = threadIdx.x;
    int x = t & 31, y = (q << 3) + (t >> 5);

    float acc[4][4] = {};
#pragma unroll
    for (int ci = 0; ci < 3; ++ci) {
        const float* ib = img + (b * 3 + ci) * 4096;
        float rv[4][4];
#pragma unroll
        for (int r = 0; r < 4; ++r) {
            int yy = 2 * y - 1 + r;
            bool yok = (unsigned)yy < 64u;
            const float* p = ib + yy * 64 + 2 * x;
            float2 c01 = yok ? *(const float2*)p : make_float2(0.f, 0.f);
            rv[r][1] = c01.x;
            rv[r][2] = c01.y;
            rv[r][0] = (yok && x > 0) ? p[-1] : 0.f;
            rv[r][3] = (yok && x < 31) ? p[2] : 0.f;
        }
#pragma unroll
        for (int j = 0; j < 4; ++j) {
            const float* wj = w + ((cog * 4 + j) * 3 + ci) * 9;
#pragma unroll
            for (int ky = 0; ky < 3; ++ky)
#pragma unroll
                for (int kx = 0; kx < 3; ++kx) {
                    float wvv = wj[ky * 3 + kx];
#pragma unroll
                    for (int py = 0; py < 2; ++py)
#pragma unroll
                        for (int px = 0; px < 2; ++px)
                            acc[j][py * 2 + px] += rv[py + ky][px + kx] * wvv;
                }
        }
    }
#pragma unroll
    for (int j = 0; j < 4; ++j) {
        int co = cog * 4 + j;
        float inv = g[co] / sqrtf(vv[co] + BN_EPS);
        float sh = cb[co] * inv + (bb[co] - m[co] * inv);
        float v0 = relu_f(acc[j][0] * inv + sh);
        float v1 = relu_f(acc[j][1] * inv + sh);
        float v2 = relu_f(acc[j][2] * inv + sh);
        float v3 = relu_f(acc[j][3] * inv + sh);
        out[((b * 64 + co) * 32 + y) * 32 + x] = fmaxf(fmaxf(v0, v1), fmaxf(v2, v3));
    }
}

// ---------------- conv2: 64->128, 3x3 SAME, SPLIT-K over ci (4 ways) ----------------
// grid 2048 = b(8) x cog(32) x half(2) x kz(4); kz in LOW bits.
// Partials stored BLOCK-LINEAR (fully coalesced): plane[kz] at ((bid*256+t)*8),
// bid = b*64+cog*2+half. The scatter to [n][128] happens once, in combine, on 4MB only.
__global__ void conv2_split(const float* __restrict__ in, const float* __restrict__ w,
                            float* __restrict__ pacc01, float* __restrict__ pacc23)
{
    int blk = blockIdx.x;
    int kz = blk & 3, half = (blk >> 2) & 1, cog = (blk >> 3) & 31, b = blk >> 8;
    int t = threadIdx.x;
    int x2p = (t & 15) * 2;
    int y = half * 16 + (t >> 4);
    bool xnz = x2p != 0;
    bool xhi = x2p == 30;
    const float* ibase = in + b * 64 * 1024 + kz * 16 * 1024;
    int xb = xnz ? x2p - 1 : 0;

    float acc[4][2] = {};

#pragma unroll 2
    for (int ci = 0; ci < 16; ++ci) {
        const float* cb2 = ibase + ci * 1024;
        float rc[3][4];
#pragma unroll
        for (int r = 0; r < 3; ++r) {
            int yy = y - 1 + r;
            bool yok = (unsigned)yy < 32u;
            const float* p = cb2 + yy * 32 + xb;
            float4 f = yok ? *(const float4*)p : make_float4(0.f, 0.f, 0.f, 0.f);
            rc[r][0] = xnz ? f.x : 0.f;
            rc[r][1] = xnz ? f.y : f.x;
            rc[r][2] = xnz ? f.z : f.y;
            float r3 = xnz ? f.w : f.z;
            rc[r][3] = xhi ? 0.f : r3;
        }
#pragma unroll
        for (int j = 0; j < 4; ++j) {
            const float* wj = w + ((cog * 4 + j) * 64 + kz * 16 + ci) * 9;
#pragma unroll
            for (int ky = 0; ky < 3; ++ky)
#pragma unroll
                for (int kx = 0; kx < 3; ++kx) {
                    float wvv = wj[ky * 3 + kx];
                    acc[j][0] += rc[ky][kx] * wvv;
                    acc[j][1] += rc[ky][kx + 1] * wvv;
                }
        }
    }

    float* pp = (kz & 2 ? pacc23 : pacc01) + (size_t)(kz & 1) * 1048576;
    int bid = b * 64 + cog * 2 + half;
    size_t base = ((size_t)bid * 256 + t) * 8;
    float4 s0 = {acc[0][0], acc[1][0], acc[2][0], acc[3][0]};
    float4 s1 = {acc[0][1], acc[1][1], acc[2][1], acc[3][1]};
    *(float4*)&pp[base] = s0;
    *(float4*)&pp[base + 4] = s1;
}

// combine 4 kz planes (block-linear layout) + bias + BN + ReLU -> x0 [n][128]
// grid 512 x 256; reads fully coalesced, scattered 16B writes only on the 4MB output
__global__ void conv2_combine(const float* __restrict__ p01, const float* __restrict__ p23,
                              const float* __restrict__ cb, const float* __restrict__ g,
                              const float* __restrict__ bb, const float* __restrict__ m,
                              const float* __restrict__ vv, float* __restrict__ x0)
{
    int gid = blockIdx.x * 256 + threadIdx.x;   // [0, 131072)
    int t = gid & 255, bid = gid >> 8;
    int half = bid & 1, cog = (bid >> 1) & 31, b = bid >> 6;
    size_t off = (size_t)gid * 8;

    float4 s0 = {0.f, 0.f, 0.f, 0.f}, s1 = {0.f, 0.f, 0.f, 0.f};
    const float* pl0 = p01;
    const float* pl1 = p01 + 1048576;
    const float* pl2 = p23;
    const float* pl3 = p23 + 1048576;
#pragma unroll
    for (int kz = 0; kz < 4; ++kz) {
        const float* pp = kz == 0 ? pl0 : kz == 1 ? pl1 : kz == 2 ? pl2 : pl3;
        float4 u0 = *(const float4*)&pp[off];
        float4 u1 = *(const float4*)&pp[off + 4];
        s0.x += u0.x; s0.y += u0.y; s0.z += u0.z; s0.w += u0.w;
        s1.x += u1.x; s1.y += u1.y; s1.z += u1.z; s1.w += u1.w;
    }

    float4 gg = ((const float4*)g)[cog];
    float4 vvv = ((const float4*)vv)[cog];
    float4 bbb = ((const float4*)bb)[cog];
    float4 mm = ((const float4*)m)[cog];
    float4 cbb = ((const float4*)cb)[cog];
    float ix = gg.x / sqrtf(vvv.x + BN_EPS);
    float iy = gg.y / sqrtf(vvv.y + BN_EPS);
    float iz = gg.z / sqrtf(vvv.z + BN_EPS);
    float iw = gg.w / sqrtf(vvv.w + BN_EPS);
    float shx = cbb.x * ix + (bbb.x - mm.x * ix);
    float shy = cbb.y * iy + (bbb.y - mm.y * iy);
    float shz = cbb.z * iz + (bbb.z - mm.z * iz);
    float shw = cbb.w * iw + (bbb.w - mm.w * iw);

    float4 o0 = {relu_f(s0.x * ix + shx), relu_f(s0.y * iy + shy),
                 relu_f(s0.z * iz + shz), relu_f(s0.w * iw + shw)};
    float4 o1 = {relu_f(s1.x * ix + shx), relu_f(s1.y * iy + shy),
                 relu_f(s1.z * iz + shz), relu_f(s1.w * iw + shw)};

    int y = half * 16 + (t >> 4), x2p = (t & 15) * 2;
    int n0 = b * 1024 + y * 32 + x2p;
    *(float4*)&x0[(size_t)n0 * 128 + cog * 4] = o0;
    *(float4*)&x0[(size_t)(n0 + 1) * 128 + cog * 4] = o1;
}

// ---------------- tiled GEMM: 32x64 tile, 128 threads, 4x4 micro ----------------
// grid (M/32, N/64). SELF: rows >= 1024 read Ahi and apply relu(a + abias) on load
// (fuses the self-loop GAT transform of the previous layer into the A-stage).
template <int K, int N, bool SELF>
__global__ void gemm32(const float* __restrict__ A, const float* __restrict__ Ahi,
                       const float* __restrict__ abias,
                       const float* __restrict__ B, float* __restrict__ C)
{
    __shared__ float As[16][32];
    __shared__ float Bs[16][64];
    int t = threadIdx.x;
    int m0 = blockIdx.x * 32;
    int n0 = blockIdx.y * 64;
    int tx = t & 15, ty = t >> 4;          // micro: rows ty*4.., cols tx*4..
    int am = t >> 2, akq = (t & 3) * 4;    // A-stage
    bool hi = SELF && m0 >= 1024;
    const float* Ab = hi ? Ahi : A;
    float acc[4][4] = {};

    for (int k0 = 0; k0 < K; k0 += 16) {
        float4 av = *(const float4*)&Ab[(size_t)(m0 + am) * K + k0 + akq];
        if (hi) {
            float4 bz = *(const float4*)&abias[k0 + akq];
            av.x = relu_f(av.x + bz.x);
            av.y = relu_f(av.y + bz.y);
            av.z = relu_f(av.z + bz.z);
            av.w = relu_f(av.w + bz.w);
        }
        float4 bv0 = *(const float4*)&B[(size_t)(k0 + ty) * N + n0 + tx * 4];
        float4 bv1 = *(const float4*)&B[(size_t)(k0 + 8 + ty) * N + n0 + tx * 4];
        __syncthreads();
        As[akq + 0][am] = av.x;
        As[akq + 1][am] = av.y;
        As[akq + 2][am] = av.z;
        As[akq + 3][am] = av.w;
        *(float4*)&Bs[ty][tx * 4] = bv0;
        *(float4*)&Bs[ty + 8][tx * 4] = bv1;
        __syncthreads();
#pragma unroll
        for (int kk = 0; kk < 16; ++kk) {
            float4 a4 = *(const float4*)&As[kk][ty * 4];
            float4 b4 = *(const float4*)&Bs[kk][tx * 4];
            float aa[4] = {a4.x, a4.y, a4.z, a4.w};
            float bb4[4] = {b4.x, b4.y, b4.z, b4.w};
#pragma unroll
            for (int i = 0; i < 4; ++i)
#pragma unroll
                for (int j = 0; j < 4; ++j)
                    acc[i][j] += aa[i] * bb4[j];
        }
    }
#pragma unroll
    for (int i = 0; i < 4; ++i) {
        float4 o = {acc[i][0], acc[i][1], acc[i][2], acc[i][3]};
        *(float4*)&C[(size_t)(m0 + ty * 4 + i) * N + n0 + tx * 4] = o;
    }
}

// ---------------- attention scores for nodes < 1024 (one wave per row) ----------------
__global__ void score_kernel(const float* __restrict__ h, const float* __restrict__ asrc,
                             const float* __restrict__ adst, float* __restrict__ s,
                             float* __restrict__ d, int D, int N)
{
    int gt = blockIdx.x * blockDim.x + threadIdx.x;
    int wave = gt >> 6, lane = gt & 63;
    if (wave >= N) return;
    const float* hp = h + (size_t)wave * D;
    float ss = 0.f, dd = 0.f;
    for (int c = lane; c < D; c += 64) {
        float hv = hp[c];
        ss += hv * asrc[c];
        dd += hv * adst[c];
    }
    for (int off = 32; off; off >>= 1) {
        ss += __shfl_down(ss, off);
        dd += __shfl_down(dd, off);
    }
    if (lane == 0) { s[wave] = ss; d[wave] = dd; }
}

// ---------------- GAT aggregation as split-K GEMM, 32x64 tile, 128 threads ----------------
// C[v,c] = sum_u exp(leaky(s[u]+d[v]) - m[v]) * h[u,c];  m[v] = leaky(smax + d[v])
// grid (32, D/64, KS); 128 threads
template <int D, int KS>
__global__ void gat_agg_gemm(const float* __restrict__ h, const float* __restrict__ s,
                             const float* __restrict__ d, float* __restrict__ pacc,
                             float* __restrict__ pden)
{
    __shared__ float Ss[1024];
    __shared__ float As[16][32];
    __shared__ float Bs[16][64];
    __shared__ float red[2];
    __shared__ float part[16][32];

    const int CH = 1024 / KS;
    int t = threadIdx.x;
    int m0 = blockIdx.x * 32;
    int n0 = blockIdx.y * 64;
    int kz = blockIdx.z;
    int tx = t & 15, ty = t >> 4;
    int ug = t >> 3, vg4 = (t & 7) * 4;   // A-gen: u-row ug, v-cols vg4..+3

    // stage s (8 per thread) + global max
    float4 sa = *(const float4*)&s[t * 8];
    float4 sb = *(const float4*)&s[t * 8 + 4];
    *(float4*)&Ss[t * 8] = sa;
    *(float4*)&Ss[t * 8 + 4] = sb;
    float lm = fmaxf(fmaxf(fmaxf(sa.x, sa.y), fmaxf(sa.z, sa.w)),
                     fmaxf(fmaxf(sb.x, sb.y), fmaxf(sb.z, sb.w)));
#pragma unroll
    for (int off = 1; off < 64; off <<= 1) lm = fmaxf(lm, __shfl_xor(lm, off));
    if ((t & 63) == 0) red[t >> 6] = lm;
    __syncthreads();
    float smax = fmaxf(red[0], red[1]);

    float4 dv = *(const float4*)&d[m0 + vg4];
    float4 mv = {leaky_f(smax + dv.x), leaky_f(smax + dv.y),
                 leaky_f(smax + dv.z), leaky_f(smax + dv.w)};
    float4 dsum = {0.f, 0.f, 0.f, 0.f};
    float acc[4][4] = {};

    for (int k0 = kz * CH; k0 < kz * CH + CH; k0 += 16) {
        float4 bv0 = *(const float4*)&h[(size_t)(k0 + ty) * D + n0 + tx * 4];
        float4 bv1 = *(const float4*)&h[(size_t)(k0 + 8 + ty) * D + n0 + tx * 4];
        float su = Ss[k0 + ug];
        float4 avv;
        avv.x = __expf(leaky_f(su + dv.x) - mv.x);
        avv.y = __expf(leaky_f(su + dv.y) - mv.y);
        avv.z = __expf(leaky_f(su + dv.z) - mv.z);
        avv.w = __expf(leaky_f(su + dv.w) - mv.w);
        dsum.x += avv.x; dsum.y += avv.y; dsum.z += avv.z; dsum.w += avv.w;
        __syncthreads();
        *(float4*)&As[ug][vg4] = avv;
        *(float4*)&Bs[ty][tx * 4] = bv0;
        *(float4*)&Bs[ty + 8][tx * 4] = bv1;
        __syncthreads();
#pragma unroll
        for (int kk = 0; kk < 16; ++kk) {
            float4 a4 = *(const float4*)&As[kk][ty * 4];
            float4 b4 = *(const float4*)&Bs[kk][tx * 4];
            float aa[4] = {a4.x, a4.y, a4.z, a4.w};
            float bb4[4] = {b4.x, b4.y, b4.z, b4.w};
#pragma unroll
            for (int i = 0; i < 4; ++i)
#pragma unroll
                for (int j = 0; j < 4; ++j)
                    acc[i][j] += aa[i] * bb4[j];
        }
    }

    __syncthreads();
    *(float4*)&part[ug][vg4] = dsum;
    __syncthreads();

#pragma unroll
    for (int i = 0; i < 4; ++i) {
        int r = ty * 4 + i;
        float4 o = {acc[i][0], acc[i][1], acc[i][2], acc[i][3]};
        *(float4*)&pacc[((size_t)kz * 1024 + m0 + r) * D + n0 + tx * 4] = o;
    }
    if (t < 32) {
        float den = 0.f;
#pragma unroll
        for (int u = 0; u < 16; ++u) den += part[u][t];
        pden[kz * 1024 + m0 + t] = den;   // redundant across n0-blocks: same value, benign
    }
}

// combine split-K partials: out[v,c] = relu(sum_ks pacc / sum_ks pden + bias), v < 1024
template <int D, int KS>
__global__ void gat_combine(const float* __restrict__ pacc, const float* __restrict__ pden,
                            const float* __restrict__ bias, float* __restrict__ out)
{
    int idx = blockIdx.x * blockDim.x + threadIdx.x;
    if (idx >= 1024 * D / 4) return;
    int c4 = idx & (D / 4 - 1);
    int v = idx / (D / 4);
    float4 a = {0.f, 0.f, 0.f, 0.f};
    float den = 0.f;
#pragma unroll
    for (int ks = 0; ks < KS; ++ks) {
        float4 p = ((const float4*)pacc)[(size_t)(ks * 1024 + v) * (D / 4) + c4];
        a.x += p.x; a.y += p.y; a.z += p.z; a.w += p.w;
        den += pden[ks * 1024 + v];
    }
    float rd = 1.f / den;
    float4 bz = ((const float4*)bias)[c4];
    float4 o = {relu_f(a.x * rd + bz.x), relu_f(a.y * rd + bz.y),
                relu_f(a.z * rd + bz.z), relu_f(a.w * rd + bz.w)};
    ((float4*)out)[(size_t)v * (D / 4) + c4] = o;
}

// ---------------- fused mean-pool + self-transform + linear head + log_softmax ----------------
// 8 blocks x 256 threads. Image 0 pools x2low rows 0..1023 (already relu'd);
// images b>=1 pool relu(h2[row]+bias2) on the fly (self-loop GAT2 output never materialized).
__global__ void poolhead(const float* __restrict__ x2low, const float* __restrict__ h2,
                         const float* __restrict__ bias2, const float* __restrict__ ow,
                         const float* __restrict__ ob, float* __restrict__ out)
{
    __shared__ float red[256];
    __shared__ float pooled[128];
    __shared__ float logits[10];
    int b = blockIdx.x, t = threadIdx.x;
    int c = t & 127, hseg = t >> 7;          // each thread: 512 rows of channel c
    float a0 = 0.f, a1 = 0.f, a2 = 0.f, a3 = 0.f;
    if (b == 0) {
        const float* p = x2low + ((size_t)hseg * 512) * 128 + c;
#pragma unroll 2
        for (int n = 0; n < 512; n += 4) {
            a0 += p[(size_t)n * 128];
            a1 += p[(size_t)(n + 1) * 128];
            a2 += p[(size_t)(n + 2) * 128];
            a3 += p[(size_t)(n + 3) * 128];
        }
    } else {
        float bz = bias2[c];
        const float* p = h2 + ((size_t)b * 1024 + hseg * 512) * 128 + c;
#pragma unroll 2
        for (int n = 0; n < 512; n += 4) {
            a0 += relu_f(p[(size_t)n * 128] + bz);
            a1 += relu_f(p[(size_t)(n + 1) * 128] + bz);
            a2 += relu_f(p[(size_t)(n + 2) * 128] + bz);
            a3 += relu_f(p[(size_t)(n + 3) * 128] + bz);
        }
    }
    red[t] = (a0 + a1) + (a2 + a3);
    __syncthreads();
    if (t < 128) pooled[t] = (red[t] + red[t + 128]) * (1.f / 1024.f);
    __syncthreads();
    if (t < 10) {
        float l = ob[t];
        for (int cc = 0; cc < 128; ++cc) l += pooled[cc] * ow[cc * 10 + t];
        logits[t] = l;
    }
    __syncthreads();
    if (t == 0) {
        float mx = logits[0];
        for (int j = 1; j < 10; ++j) mx = fmaxf(mx, logits[j]);
        float sum = 0.f;
        for (int j = 0; j < 10; ++j) sum += expf(logits[j] - mx);
        float lse = mx + logf(sum);
        for (int j = 0; j < 10; ++j) out[b * 10 + j] = logits[j] - lse;
    }
}

extern "C" void kernel_launch(void* const* d_in, const int* in_sizes, int n_in,
                              void* d_out, int out_size, void* d_ws, size_t ws_size,
                              hipStream_t stream)
{
    const float* images = (const float*)d_in[0];
    const float* c1w = (const float*)d_in[1];
    const float* c1b = (const float*)d_in[2];
    const float* bn1g = (const float*)d_in[3];
    const float* bn1b = (const float*)d_in[4];
    const float* bn1m = (const float*)d_in[5];
    const float* bn1v = (const float*)d_in[6];
    const float* c2w = (const float*)d_in[7];
    const float* c2b = (const float*)d_in[8];
    const float* bn2g = (const float*)d_in[9];
    const float* bn2b = (const float*)d_in[10];
    const float* bn2m = (const float*)d_in[11];
    const float* bn2v = (const float*)d_in[12];
    const float* g1w = (const float*)d_in[13];
    const float* g1as = (const float*)d_in[14];
    const float* g1ad = (const float*)d_in[15];
    const float* g1b = (const float*)d_in[16];
    const float* g2w = (const float*)d_in[17];
    const float* g2as = (const float*)d_in[18];
    const float* g2ad = (const float*)d_in[19];
    const float* g2b = (const float*)d_in[20];
    const float* ow = (const float*)d_in[21];
    const float* ob = (const float*)d_in[22];
    float* out = (float*)d_out;

    // ws layout (floats):
    // [x1 2097152][bufc1 524288][h1 2097152][x0 1048576][h2 1048576][s1,d1,s2,d2]
    // conv2 split planes 0/1 alias x1-region, planes 2/3 alias h1-region (both dead then).
    // h1 overwritten by gemm1 after combine reads planes. pacc1 aliases x0+h2 (dead).
    // pacc2 aliases h1 (dead after gemm2, its last reader). combine2 -> x2 = x0 (dead).
    // pden1/pden2 alias bufc1 (dead after conv2_split).
    float* ws = (float*)d_ws;
    float* x1    = ws;                   // 2,097,152
    float* bufc1 = ws + 2097152;         //   524,288
    float* h1    = ws + 2621440;         // 2,097,152
    float* x0    = ws + 4718592;         // 1,048,576
    float* h2    = ws + 5767168;         // 1,048,576
    float* s1    = ws + 6815744;         // 1,024
    float* d1    = ws + 6816768;
    float* s2    = ws + 6817792;
    float* d2    = ws + 6818816;
    float* pden1 = bufc1 + 16384;        // 8,192
    float* pden2 = bufc1 + 24576;        // 16,384
    float* pacc1 = x0;                   // 8*1024*256 = 2,097,152 (spans x0+h2)
    float* pacc2 = h1;                   // 16*1024*128 = 2,097,152
    float* x2    = x0;
    float* c2p01 = x1;                   // conv2 split planes 0,1 (2*1,048,576)
    float* c2p23 = h1;                   // conv2 split planes 2,3 (2*1,048,576)

    conv1_pool<<<512, 256, 0, stream>>>(images, c1w, c1b, bn1g, bn1b, bn1m, bn1v, bufc1);
    conv2_split<<<2048, 256, 0, stream>>>(bufc1, c2w, c2p01, c2p23);
    conv2_combine<<<512, 256, 0, stream>>>(c2p01, c2p23, c2b, bn2g, bn2b, bn2m, bn2v, x0);

    gemm32<128, 256, false><<<dim3(256, 4), 128, 0, stream>>>(x0, x0, nullptr, g1w, h1);
    score_kernel<<<256, 256, 0, stream>>>(h1, g1as, g1ad, s1, d1, 256, 1024);
    gat_agg_gemm<256, 8><<<dim3(32, 4, 8), 128, 0, stream>>>(h1, s1, d1, pacc1, pden1);
    gat_combine<256, 8><<<256, 256, 0, stream>>>(pacc1, pden1, g1b, x1);

    // gemm2: rows <1024 from x1 (combined GAT1 output), rows >=1024 = relu(h1+g1b) fused
    gemm32<256, 128, true><<<dim3(256, 2), 128, 0, stream>>>(x1, h1, g1b, g2w, h2);
    score_kernel<<<256, 256, 0, stream>>>(h2, g2as, g2ad, s2, d2, 128, 1024);
    gat_agg_gemm<128, 16><<<dim3(32, 2, 16), 128, 0, stream>>>(h2, s2, d2, pacc2, pden2);
    gat_combine<128, 16><<<128, 256, 0, stream>>>(pacc2, pden2, g2b, x2);

    poolhead<<<8, 256, 0, stream>>>(x2, h2, g2b, ow, ob, out);
}